// Round 1
// baseline (339.010 us; speedup 1.0000x reference)
//
#include <hip/hip_runtime.h>
#include <stdint.h>

#define TWO_PI_F 6.28318530717958647692f
#define EPSF 1e-6f
#define DTF 0.01f
#define KCOUP 2.0f

#define NCOLP 768            // padded col count (24 tiles of 32); real cols = 672
#define NKC 64               // K chunks (2048 / 32)
#define CHUNK_B (NCOLP * 64) // 49152 bytes per K-chunk B image (col*64B, 32 bf16)
#define BM 64
#define THREADS 512
#define AS_STRIDE 36                       // bf16 elems per A row (pad 32->36 for banks)
#define AS_BYTES (BM * AS_STRIDE * 2)      // 4608
#define LDS_BYTES (CHUNK_B + AS_BYTES)     // 53760

typedef __attribute__((ext_vector_type(8)))  __bf16        bf16x8;
typedef __attribute__((ext_vector_type(8)))  unsigned short ushort8v;
typedef __attribute__((ext_vector_type(4)))  unsigned short ushort4v;
typedef __attribute__((ext_vector_type(16))) float          f32x16;

__device__ __forceinline__ unsigned short f2bf(float f) {
  unsigned u = __builtin_bit_cast(unsigned, f);
  u = (u + 0x7FFFu + ((u >> 16) & 1u)) >> 16;   // RNE
  return (unsigned short)u;
}

// ---------------- prep: W (f32) -> swizzled bf16 LDS-image in ws ----------------
__global__ void prep_w(const float* __restrict__ Wd, const float* __restrict__ Wt,
                       const float* __restrict__ Wg, unsigned short* __restrict__ wb) {
  int t = blockIdx.x * blockDim.x + threadIdx.x;
  if (t >= NCOLP * NKC) return;
  int col = t >> 6, kc = t & 63;
  unsigned short vals[32];
  if (col < 672) {
    const float* src = (col < 32)  ? Wd + (size_t)col * 2048
                     : (col < 160) ? Wt + (size_t)(col - 32) * 2048
                                   : Wg + (size_t)(col - 160) * 2048;
    src += kc * 32;
    #pragma unroll
    for (int j = 0; j < 32; j += 4) {
      float4 v = *(const float4*)(src + j);
      vals[j] = f2bf(v.x); vals[j + 1] = f2bf(v.y);
      vals[j + 2] = f2bf(v.z); vals[j + 3] = f2bf(v.w);
    }
  } else {
    #pragma unroll
    for (int j = 0; j < 32; j++) vals[j] = 0;  // phantom cols: zero weights
  }
  const int sw = (col >> 1) & 3;
  unsigned short* dst = wb + ((size_t)kc * CHUNK_B + (size_t)col * 64) / 2;
  #pragma unroll
  for (int o = 0; o < 4; o++) {           // octet o holds k = o*8 .. o*8+7
    int slot = o ^ sw;                    // bank swizzle
    ushort8v v8;
    #pragma unroll
    for (int jj = 0; jj < 8; jj++) v8[jj] = vals[o * 8 + jj];
    *(ushort8v*)(dst + slot * 8) = v8;
  }
}

// ---------------- fused: GEMM (bf16 MFMA) + Kuramoto dynamics + epilogue ----------------
__launch_bounds__(THREADS, 2)
__global__ void fused(const float* __restrict__ x, const unsigned short* __restrict__ wb,
                      const float* __restrict__ pdt_p, const float* __restrict__ ptg_p,
                      float* __restrict__ out) {
  __shared__ __align__(16) char smem[LDS_BYTES];
  unsigned short* Bs = (unsigned short*)smem;
  unsigned short* As = (unsigned short*)(smem + CHUNK_B);

  const int tid = threadIdx.x;
  const int wid = tid >> 6, lane = tid & 63;
  const int wr = wid >> 2, wc = wid & 3;      // 2 x 4 wave grid
  const int r = lane & 31, hk = lane >> 5;    // col-in-tile / k-half
  const size_t row0 = (size_t)blockIdx.x * BM;

  f32x16 acc[6];
  #pragma unroll
  for (int t = 0; t < 6; t++)
    #pragma unroll
    for (int j = 0; j < 16; j++) acc[t][j] = 0.f;

  // A staging: thread -> (row, 16B of f32)
  const int arow = tid >> 3, aq = tid & 7;
  const float4* agp4 = (const float4*)(x + (row0 + arow) * 2048) + aq;
  unsigned short* awp = As + arow * AS_STRIDE + aq * 4;

  const int afrag_base = (wr * 32 + r) * AS_STRIDE + hk * 8;
  const int bsw = (r >> 1) & 3;

  float4 av = *agp4;                          // prefetch chunk 0
  for (int kc = 0; kc < NKC; kc++) {
    __syncthreads();                          // previous compute done
    // stage B: 6 exact wave-rounds of global_load_lds (16B/lane)
    {
      const char* src = (const char*)wb + (size_t)kc * CHUNK_B;
      #pragma unroll
      for (int rnd = 0; rnd < 6; rnd++) {
        int ofs = wid * 1024 + rnd * 8192 + lane * 16;
        __builtin_amdgcn_global_load_lds(
            (const __attribute__((address_space(1))) void*)(src + ofs),
            (__attribute__((address_space(3))) void*)(smem + ofs), 16, 0, 0);
      }
    }
    // stage A from previously-prefetched registers
    {
      ushort4v a4;
      a4[0] = f2bf(av.x); a4[1] = f2bf(av.y); a4[2] = f2bf(av.z); a4[3] = f2bf(av.w);
      *(ushort4v*)awp = a4;
    }
    __syncthreads();
    if (kc + 1 < NKC) av = agp4[(kc + 1) * 8];   // prefetch next chunk's A (hides under MFMA)

    #pragma unroll
    for (int m = 0; m < 2; m++) {               // two K=16 MFMAs per 32-K chunk
      ushort4v al = *(ushort4v*)(As + afrag_base + m * 16);
      ushort4v ah = *(ushort4v*)(As + afrag_base + m * 16 + 4);
      ushort8v avv;
      #pragma unroll
      for (int j = 0; j < 4; j++) { avv[j] = al[j]; avv[4 + j] = ah[j]; }
      bf16x8 afr = __builtin_bit_cast(bf16x8, avv);
      #pragma unroll
      for (int ti = 0; ti < 6; ti++) {
        int gcol = (wc * 6 + ti) * 32 + r;
        int slot = (m * 2 + hk) ^ bsw;
        ushort8v bv = *(ushort8v*)(Bs + gcol * 32 + slot * 8);
        bf16x8 bfr = __builtin_bit_cast(bf16x8, bv);
        acc[ti] = __builtin_amdgcn_mfma_f32_32x32x16_bf16(afr, bfr, acc[ti], 0, 0, 0);
      }
    }
  }

  // ---------------- dynamics ----------------
  __syncthreads();
  float* zdt  = (float*)smem;                 // [64][161] f32 (aliases Bs)
  float* Fbuf = (float*)(smem + 64 * 161 * 4);// [2][64]

  if (wc == 0) {                              // wc0 owns tiles 0..5 => cols 0..159 in tiles 0..4
    #pragma unroll
    for (int ti = 0; ti < 5; ti++) {
      int gcol = ti * 32 + r;
      #pragma unroll
      for (int reg = 0; reg < 16; reg++) {
        int row = wr * 32 + (reg & 3) + ((reg >> 2) << 3) + (hk << 2);
        zdt[row * 161 + gcol] = acc[ti][reg];
      }
    }
  }
  __syncthreads();

  const float pdt = fminf(fmaxf(pdt_p[0], 0.f), 1.f);
  const float ptg = fminf(fmaxf(ptg_p[0], 0.f), 1.f);

  for (int rr = 0; rr < 8; rr++) {            // each wave: 8 rows
    int row = wid * 8 + rr;
    float pd  = (lane < 32) ? zdt[row * 161 + lane] : 0.f;
    float pt0 = zdt[row * 161 + 32 + lane];
    float pt1 = zdt[row * 161 + 96 + lane];
    float Ft = 1.f, Fg = 1.f;
    for (int s = 0; s < 10; s++) {
      float sd = __sinf(pd),  cd = __cosf(pd);
      float s0 = __sinf(pt0), c0 = __cosf(pt0);
      float s1 = __sinf(pt1), c1 = __cosf(pt1);
      float vCd = (lane < 32) ? cd : 0.f;
      float vSd = (lane < 32) ? sd : 0.f;
      float vCt = c0 + c1, vSt = s0 + s1;
      #pragma unroll
      for (int off = 32; off > 0; off >>= 1) {
        vCd += __shfl_xor(vCd, off);
        vSd += __shfl_xor(vSd, off);
        vCt += __shfl_xor(vCt, off);
        vSt += __shfl_xor(vSt, off);
      }
      float Cd = vCd * (1.f / 32.f),  Sd = vSd * (1.f / 32.f);
      float Ct = vCt * (1.f / 128.f), St = vSt * (1.f / 128.f);
      pd  += DTF * (TWO_PI_F * 2.f + KCOUP * (Sd * cd - Cd * sd));
      pt0 += DTF * (TWO_PI_F * 6.f + KCOUP * (St * c0 - Ct * s0));
      pt1 += DTF * (TWO_PI_F * 6.f + KCOUP * (St * c1 - Ct * s1));
      float rd = sqrtf(Cd * Cd + Sd * Sd) + EPSF;
      float rt = sqrtf(Ct * Ct + St * St) + EPSF;
      Ft *= (1.f + DTF * pdt * (Cd / rd));
      Fg *= (1.f + DTF * ptg * (Ct / rt));
    }
    if (lane == 0) { Fbuf[row] = Ft; Fbuf[64 + row] = Fg; }
  }
  __syncthreads();

  // ---------------- epilogue: amplitudes * factors ----------------
  #pragma unroll
  for (int ti = 0; ti < 6; ti++) {
    int ct = wc * 6 + ti;
    if (ct < 21) {                            // skip phantom tiles (cols >= 672)
      int gcol = ct * 32 + r;
      #pragma unroll
      for (int reg = 0; reg < 16; reg++) {
        int row = wr * 32 + (reg & 3) + ((reg >> 2) << 3) + (hk << 2);
        float z = acc[ti][reg];
        float a = fmaxf(fabsf(z), EPSF);
        float f = (ct == 0) ? 1.f : (ct < 5 ? Fbuf[row] : Fbuf[64 + row]);
        out[(row0 + row) * 672 + gcol] = fmaxf(a * f, EPSF);
      }
    }
  }
}

extern "C" void kernel_launch(void* const* d_in, const int* in_sizes, int n_in,
                              void* d_out, int out_size, void* d_ws, size_t ws_size,
                              hipStream_t stream) {
  const float* x   = (const float*)d_in[0];
  const float* Wd  = (const float*)d_in[1];
  const float* Wt  = (const float*)d_in[2];
  const float* Wg  = (const float*)d_in[3];
  const float* pdt = (const float*)d_in[4];
  const float* ptg = (const float*)d_in[5];
  float* outp = (float*)d_out;
  unsigned short* wb = (unsigned short*)d_ws;

  if (ws_size < (size_t)NKC * CHUNK_B) return;  // need 3 MiB scratch

  const int Brows = in_sizes[0] / 2048;         // 32768
  prep_w<<<(NCOLP * NKC + 255) / 256, 256, 0, stream>>>(Wd, Wt, Wg, wb);
  fused<<<Brows / BM, THREADS, 0, stream>>>(x, wb, pdt, ptg, outp);
}